// Round 6
// baseline (499.624 us; speedup 1.0000x reference)
//
#include <hip/hip_runtime.h>

#define Bsz 64
#define Tsz 2048
#define Esz 512
#define Asz 128
#define Rsz 1024
#define KP  576      // 512 (E) + 62 conv taps + 2 zero pad
#define TILE_M 32
#define CHUNKS (Tsz / TILE_M)   // 64

typedef __bf16 bf16;
typedef __bf16 bf16x8 __attribute__((ext_vector_type(8)));
typedef __bf16 bf16x4 __attribute__((ext_vector_type(4)));
typedef __bf16 bf16x2 __attribute__((ext_vector_type(2)));
typedef float  f32x4  __attribute__((ext_vector_type(4)));

// Wext layout: [72 kgroups][128 a][8] bf16 -> element (a,k) at [k>>3][a][k&7].

// ---------------- prep ----------------
__global__ __launch_bounds__(256) void prep_kernel(
    const float* __restrict__ Wmem, const float* __restrict__ convw,
    const float* __restrict__ Wloc, const float* __restrict__ ah,
    const float* __restrict__ Wq, bf16* __restrict__ Wext,
    float* __restrict__ pq)
{
  __shared__ f32x4 red[256];
  int blk = blockIdx.x, tid = threadIdx.x;
  if (blk < 128) {
    int a = blk;
    #pragma unroll
    for (int e = tid; e < Esz; e += 256)
      Wext[(size_t)(e >> 3)*(Asz*8) + a*8 + (e & 7)] = (bf16)Wmem[e*Asz + a];
  } else if (blk < 160) {
    int idx = (blk - 128)*256 + tid;      // 8192 = 128 a x 64 j
    int a = idx >> 6, j = idx & 63;
    float u = 0.f;
    if (j < 62) {
      int c  = (j < 31) ? 0 : 1;
      int kk = (j < 31) ? j : j - 31;
      #pragma unroll
      for (int f = 0; f < 32; ++f)
        u += convw[f*62 + c*31 + kk] * Wloc[f*Asz + a];
    }
    Wext[(size_t)(64 + (j >> 3))*(Asz*8) + a*8 + (j & 7)] = (bf16)u;
  } else {
    int b  = blk - 160;
    int cg = tid & 31;
    int kg = tid >> 5;
    const float* ahb = ah + (size_t)b*Rsz;
    f32x4 s = (f32x4){0.f,0.f,0.f,0.f};
    int r0 = kg*128;
    for (int r = r0; r < r0 + 128; ++r) {
      float av = ahb[r];
      f32x4 wq = *(const f32x4*)&Wq[r*Asz + cg*4];
      s += av * wq;
    }
    red[tid] = s;
    __syncthreads();
    if (tid < 32) {
      f32x4 tot = red[tid];
      #pragma unroll
      for (int g = 1; g < 8; ++g) tot += red[g*32 + tid];
      *(f32x4*)&pq[b*Asz + tid*4] = tot;
    }
  }
}

__device__ __forceinline__ float tanh_fast(float x) {
  float ex = __expf(2.f * x);
  return 1.f - 2.f / (ex + 1.f);
}

// stage im2col'd aw window into K columns 512..575 (32x64 = 8 per thread)
__device__ __forceinline__ void stage_aw(bf16* Afull, const float* aw,
                                         int t0p, int tid) {
  #pragma unroll
  for (int p = 0; p < 8; ++p) {
    int i = tid + p*256;
    int r = i >> 6, j = i & 63;
    float val = 0.f;
    if (j < 62) {
      int c  = (j < 31) ? 0 : 1;
      int kk = (j < 31) ? j : j - 31;
      int t  = t0p + r + kk - 15;
      if (t >= 0 && t < Tsz) val = aw[c*Tsz + t];
    }
    int k = Esz + j;
    int sw = (k >> 3) ^ (r & 7);
    Afull[r*KP + sw*8 + (k & 7)] = (bf16)val;
  }
}

// convert staged registers -> bf16 LDS (XOR-chunk swizzled)
__device__ __forceinline__ void write_tile(bf16* Afull, const f32x4* st, int tid) {
  #pragma unroll
  for (int p = 0; p < 16; ++p) {
    int i = tid + p*256;
    int r = i >> 7, c4 = i & 127;
    int k = c4 * 4;
    int sw = (k >> 3) ^ (r & 7);
    bf16x4 pk;
    pk[0] = (bf16)st[p][0]; pk[1] = (bf16)st[p][1];
    pk[2] = (bf16)st[p][2]; pk[3] = (bf16)st[p][3];
    *(bf16x4*)&Afull[r*KP + sw*8 + (k & 7)] = pk;
  }
}

// K-loop + energies + align + out-partial for one staged 32-row chunk
template<bool USE_POUT>
__device__ __forceinline__ void compute_chunk(
    const bf16* Afull, const float* s_pq, const float* s_vw,
    float* s_ebuf, float* s_align, const bf16x8* wv,
    const int* __restrict__ mask, const float* __restrict__ vb,
    float* __restrict__ pout, float* __restrict__ outg,
    float* __restrict__ ws_align, int b, int t0p, int cid, int tid)
{
  int w = tid >> 6, l = tid & 63;
  int quad = l >> 4, lrow = l & 15;
  int acol0 = w*32 + lrow, acol1 = acol0 + 16;

  f32x4 acc[2][2] = {};
  bf16x8 bnext0 = wv[quad*Asz + acol0];
  bf16x8 bnext1 = wv[quad*Asz + acol1];

  // K loop: 18 chunks of 32 (512 memory + 64 location), B pipelined 1 ahead
  for (int kc = 0; kc < KP/32; ++kc) {
    bf16x8 bfrag0 = bnext0, bfrag1 = bnext1;
    if (kc < KP/32 - 1) {
      int kg2 = (kc+1)*4 + quad;
      bnext0 = wv[kg2*Asz + acol0];
      bnext1 = wv[kg2*Asz + acol1];
    }
    int kg = kc*4 + quad;
    bf16x8 afrag[2];
    #pragma unroll
    for (int mt = 0; mt < 2; ++mt) {
      int row = mt*16 + lrow;
      afrag[mt] = *(const bf16x8*)&Afull[row*KP + ((kg ^ (row & 7)) << 3)];
    }
    #pragma unroll
    for (int mt = 0; mt < 2; ++mt) {
      acc[mt][0] = __builtin_amdgcn_mfma_f32_16x16x32_bf16(afrag[mt], bfrag0, acc[mt][0], 0, 0, 0);
      acc[mt][1] = __builtin_amdgcn_mfma_f32_16x16x32_bf16(afrag[mt], bfrag1, acc[mt][1], 0, 0, 0);
    }
  }

  // energies: e_r = sum_a tanh(pm+pl+pq)*v_w  (C layout: col=lane&15, row=quad*4+reg)
  float partial[2][4];
  #pragma unroll
  for (int mt = 0; mt < 2; ++mt)
    #pragma unroll
    for (int rg = 0; rg < 4; ++rg) partial[mt][rg] = 0.f;
  #pragma unroll
  for (int nt = 0; nt < 2; ++nt) {
    int col = w*32 + nt*16 + lrow;
    float vwc = s_vw[col], pqc = s_pq[col];
    #pragma unroll
    for (int mt = 0; mt < 2; ++mt)
      #pragma unroll
      for (int rg = 0; rg < 4; ++rg)
        partial[mt][rg] += tanh_fast(acc[mt][nt][rg] + pqc) * vwc;
  }
  #pragma unroll
  for (int off = 1; off < 16; off <<= 1)
    #pragma unroll
    for (int mt = 0; mt < 2; ++mt)
      #pragma unroll
      for (int rg = 0; rg < 4; ++rg)
        partial[mt][rg] += __shfl_xor(partial[mt][rg], off, 64);
  if (lrow == 0) {
    #pragma unroll
    for (int mt = 0; mt < 2; ++mt)
      #pragma unroll
      for (int rg = 0; rg < 4; ++rg)
        atomicAdd(&s_ebuf[mt*16 + quad*4 + rg], partial[mt][rg]);
  }
  __syncthreads();

  if (tid < TILE_M) {
    int t = t0p + tid;
    float al = s_ebuf[tid] + vb[0] + (float)mask[b*Tsz + t] * -1e25f;
    s_align[tid] = al;
    ws_align[b*Tsz + t] = al;
  }
  __syncthreads();

  // attention_output partial: sum_r align[r] * mem[r,e] over this 32-row chunk
  int k0 = tid * 2;
  float a0 = 0.f, a1 = 0.f;
  #pragma unroll
  for (int r = 0; r < TILE_M; ++r) {
    float al = s_align[r];
    int sw = ((k0 >> 3) ^ (r & 7));
    bf16x2 m = *(const bf16x2*)&Afull[r*KP + sw*8 + (k0 & 7)];
    a0 += al * (float)m[0];
    a1 += al * (float)m[1];
  }
  if constexpr (USE_POUT) {
    float2 o; o.x = a0; o.y = a1;
    *(float2*)&pout[(size_t)cid * Esz + k0] = o;
  } else {
    atomicAdd(&outg[b*Esz + k0],     a0);
    atomicAdd(&outg[b*Esz + k0 + 1], a1);
  }
}

// ---------------- main fused kernel: 2 chunks/block, T14 prefetch overlap -----
// Chunk 1's 16 nt global loads are issued into registers BEFORE chunk 0's
// K-loop, hiding their HBM latency under ~1400 cycles of MFMA + epilogue.
template<bool USE_POUT>
__global__ __launch_bounds__(256, 3) void attn_main(
    const float* __restrict__ memory, const float* __restrict__ awcat,
    const int* __restrict__ mask, const bf16* __restrict__ Wext,
    const float* __restrict__ pq, const float* __restrict__ vw,
    const float* __restrict__ vb, float* __restrict__ pout,
    float* __restrict__ outg, float* __restrict__ ws_align)
{
  __shared__ bf16  Afull[TILE_M * KP];   // 36864 B, XOR-chunk swizzled
  __shared__ float s_pq[Asz];
  __shared__ float s_vw[Asz];
  __shared__ float s_ebuf[TILE_M];
  __shared__ float s_align[TILE_M];

  int tid = threadIdx.x;
  int bp = blockIdx.x;                   // 2048 = 64 b x 32 pairs
  int b  = bp >> 5;
  int t0 = (bp & 31) << 6;               // 64-row pair base

  const bf16x8* wv = (const bf16x8*)Wext;
  const float*  aw = awcat + (size_t)b*2*Tsz;
  const f32x4*  memv = (const f32x4*)(memory + (size_t)(b*Tsz + t0)*Esz);

  // ---- chunk 0: issue all 16 nt loads, then convert+write ----
  f32x4 st[16];
  #pragma unroll
  for (int p = 0; p < 16; ++p) {
    int i = tid + p*256;
    st[p] = __builtin_nontemporal_load(memv + (i >> 7)*128 + (i & 127));
  }
  write_tile(Afull, st, tid);
  stage_aw(Afull, aw, t0, tid);
  if (tid < Asz) { s_pq[tid] = pq[b*Asz + tid]; s_vw[tid] = vw[tid]; }
  if (tid < TILE_M) s_ebuf[tid] = 0.f;
  __syncthreads();

  // ---- issue chunk 1 loads (in flight across chunk-0 compute) ----
  const f32x4* memv1 = memv + 32*(Esz/4);
  #pragma unroll
  for (int p = 0; p < 16; ++p) {
    int i = tid + p*256;
    st[p] = __builtin_nontemporal_load(memv1 + (i >> 7)*128 + (i & 127));
  }

  compute_chunk<USE_POUT>(Afull, s_pq, s_vw, s_ebuf, s_align, wv, mask, vb,
                          pout, outg, ws_align, b, t0, bp << 1, tid);
  __syncthreads();                       // chunk-0 LDS reads complete

  // ---- chunk 1: write prefetched tile, recompute ----
  write_tile(Afull, st, tid);
  stage_aw(Afull, aw, t0 + 32, tid);
  if (tid < TILE_M) s_ebuf[tid] = 0.f;
  __syncthreads();

  compute_chunk<USE_POUT>(Afull, s_pq, s_vw, s_ebuf, s_align, wv, mask, vb,
                          pout, outg, ws_align, b, t0 + 32, (bp << 1) | 1, tid);
}

// ---------------- softmax over T per batch row (+ optional out reduction) ----
template<bool REDUCE>
__global__ __launch_bounds__(256) void softmax_kernel(
    const float* __restrict__ ws_align, const float* __restrict__ pout,
    float* __restrict__ out_be, float* __restrict__ out_w)
{
  int b = blockIdx.x, tid = threadIdx.x;
  const float* row = ws_align + (size_t)b*Tsz;
  float vals[8];
  float lmax = -3.4e38f;
  #pragma unroll
  for (int i = 0; i < 8; ++i) { vals[i] = row[tid + i*256]; lmax = fmaxf(lmax, vals[i]); }
  #pragma unroll
  for (int off = 1; off < 64; off <<= 1) lmax = fmaxf(lmax, __shfl_xor(lmax, off, 64));
  __shared__ float smax[4], ssum[4];
  if ((tid & 63) == 0) smax[tid >> 6] = lmax;
  __syncthreads();
  float bmax = fmaxf(fmaxf(smax[0], smax[1]), fmaxf(smax[2], smax[3]));
  float lsum = 0.f;
  #pragma unroll
  for (int i = 0; i < 8; ++i) { vals[i] = __expf(vals[i] - bmax); lsum += vals[i]; }
  #pragma unroll
  for (int off = 1; off < 64; off <<= 1) lsum += __shfl_xor(lsum, off, 64);
  if ((tid & 63) == 0) ssum[tid >> 6] = lsum;
  __syncthreads();
  float inv = 1.f / (ssum[0] + ssum[1] + ssum[2] + ssum[3]);
  #pragma unroll
  for (int i = 0; i < 8; ++i) out_w[(size_t)b*Tsz + tid + i*256] = vals[i] * inv;

  if constexpr (REDUCE) {
    // out[b,e] = sum_{c<CHUNKS} pout[(b*CHUNKS+c)*E + e]   (8 MB L2-warm read)
    float2 s; s.x = 0.f; s.y = 0.f;
    const float2* pv = (const float2*)(pout + (size_t)b*CHUNKS*Esz) + tid;
    #pragma unroll
    for (int c = 0; c < CHUNKS; ++c) {
      float2 v = pv[(size_t)c * (Esz/2)];
      s.x += v.x; s.y += v.y;
    }
    *(float2*)&out_be[(size_t)b*Esz + tid*2] = s;
  }
}

extern "C" void kernel_launch(void* const* d_in, const int* in_sizes, int n_in,
                              void* d_out, int out_size, void* d_ws, size_t ws_size,
                              hipStream_t stream) {
  const float* ah   = (const float*)d_in[0];
  const float* mem  = (const float*)d_in[1];
  const float* awc  = (const float*)d_in[2];
  const int*   mask = (const int*)d_in[3];
  const float* Wq   = (const float*)d_in[4];
  const float* Wm   = (const float*)d_in[5];
  const float* cw   = (const float*)d_in[6];
  const float* Wl   = (const float*)d_in[7];
  const float* vw   = (const float*)d_in[8];
  const float* vb   = (const float*)d_in[9];
  float* out = (float*)d_out;

  // ws layout: Wext bf16 [72][128][8] (147456 B) | pq f32 (32768 B)
  //            | align f32 [64][2048] (524288 B) | pout f32 [4096][512] (8 MB)
  bf16*  Wext = (bf16*)d_ws;
  float* pq   = (float*)((char*)d_ws + 147456);
  float* wsa  = (float*)((char*)d_ws + 180224);
  float* pout = (float*)((char*)d_ws + 180224 + (size_t)Bsz*Tsz*4);

  size_t need = 180224 + (size_t)Bsz*Tsz*4 + (size_t)Bsz*CHUNKS*Esz*4;

  prep_kernel<<<dim3(224), 256, 0, stream>>>(Wm, cw, Wl, ah, Wq, Wext, pq);
  if (ws_size >= need) {
    attn_main<true><<<dim3(Bsz*CHUNKS/2), 256, 0, stream>>>(
        mem, awc, mask, Wext, pq, vw, vb, pout, out, wsa);
    softmax_kernel<true><<<dim3(Bsz), 256, 0, stream>>>(wsa, pout, out, out + Bsz*Esz);
  } else {
    // fallback: round-0-verified atomic epilogue (no pout buffer needed)
    hipMemsetAsync(out, 0, Bsz*Esz*sizeof(float), stream);
    attn_main<false><<<dim3(Bsz*CHUNKS/2), 256, 0, stream>>>(
        mem, awc, mask, Wext, pq, vw, vb, wsa /*unused*/, out, wsa);
    softmax_kernel<false><<<dim3(Bsz), 256, 0, stream>>>(wsa, wsa, out, out + Bsz*Esz);
  }
}

// Round 7
// 433.984 us; speedup vs baseline: 1.1513x; 1.1513x over previous
//
#include <hip/hip_runtime.h>

#define Bsz 64
#define Tsz 2048
#define Esz 512
#define Asz 128
#define Rsz 1024
#define KP  576      // 512 (E) + 62 conv taps + 2 zero pad
#define TILE_M 32
#define CHUNKS (Tsz / TILE_M)   // 64

typedef __bf16 bf16;
typedef __bf16 bf16x8 __attribute__((ext_vector_type(8)));
typedef __bf16 bf16x4 __attribute__((ext_vector_type(4)));
typedef __bf16 bf16x2 __attribute__((ext_vector_type(2)));
typedef float  f32x4  __attribute__((ext_vector_type(4)));

// Wext layout: [72 kgroups][128 a][8] bf16 -> element (a,k) at [k>>3][a][k&7].
// B-fragment wave-load = 64 lanes x 16 B spanning 4 kgroups x 16 acols -> 8 dense
// 128B lines.

// ---------------- prep ----------------
__global__ __launch_bounds__(256) void prep_kernel(
    const float* __restrict__ Wmem, const float* __restrict__ convw,
    const float* __restrict__ Wloc, const float* __restrict__ ah,
    const float* __restrict__ Wq, bf16* __restrict__ Wext,
    float* __restrict__ pq)
{
  __shared__ f32x4 red[256];
  int blk = blockIdx.x, tid = threadIdx.x;
  if (blk < 128) {
    int a = blk;
    #pragma unroll
    for (int e = tid; e < Esz; e += 256)
      Wext[(size_t)(e >> 3)*(Asz*8) + a*8 + (e & 7)] = (bf16)Wmem[e*Asz + a];
  } else if (blk < 160) {
    int idx = (blk - 128)*256 + tid;      // 8192 = 128 a x 64 j
    int a = idx >> 6, j = idx & 63;
    float u = 0.f;
    if (j < 62) {
      int c  = (j < 31) ? 0 : 1;
      int kk = (j < 31) ? j : j - 31;
      #pragma unroll
      for (int f = 0; f < 32; ++f)
        u += convw[f*62 + c*31 + kk] * Wloc[f*Asz + a];
    }
    Wext[(size_t)(64 + (j >> 3))*(Asz*8) + a*8 + (j & 7)] = (bf16)u;
  } else {
    int b  = blk - 160;
    int cg = tid & 31;
    int kg = tid >> 5;
    const float* ahb = ah + (size_t)b*Rsz;
    f32x4 s = (f32x4){0.f,0.f,0.f,0.f};
    int r0 = kg*128;
    for (int r = r0; r < r0 + 128; ++r) {
      float av = ahb[r];
      f32x4 wq = *(const f32x4*)&Wq[r*Asz + cg*4];
      s += av * wq;
    }
    red[tid] = s;
    __syncthreads();
    if (tid < 32) {
      f32x4 tot = red[tid];
      #pragma unroll
      for (int g = 1; g < 8; ++g) tot += red[g*32 + tid];
      *(f32x4*)&pq[b*Asz + tid*4] = tot;
    }
  }
}

__device__ __forceinline__ float tanh_fast(float x) {
  float ex = __expf(2.f * x);
  return 1.f - 2.f / (ex + 1.f);
}

// ---------------- main fused kernel (32-row tiles, 4 blocks/CU) ----------------
// memory staged with NON-TEMPORAL loads (268 MB streamed once; keep Wext hot in
// L2). B-fragments software-pipelined one kc ahead so L2 latency overlaps MFMAs.
// Round-6 lesson: deeper register prefetch (2 chunks/block) drops occupancy
// 4->2 blocks/CU and regresses +62us — inter-block TLP at 16 waves/CU is the
// latency-hiding mechanism; do not spend VGPRs on explicit pipelining.
template<bool USE_POUT>
__global__ __launch_bounds__(256, 4) void attn_main(
    const float* __restrict__ memory, const float* __restrict__ awcat,
    const int* __restrict__ mask, const bf16* __restrict__ Wext,
    const float* __restrict__ pq, const float* __restrict__ vw,
    const float* __restrict__ vb, float* __restrict__ pout,
    float* __restrict__ outg, float* __restrict__ ws_align)
{
  __shared__ bf16  Afull[TILE_M * KP];   // 36864 B, XOR-chunk swizzled
  __shared__ float s_pq[Asz];
  __shared__ float s_vw[Asz];
  __shared__ float s_ebuf[TILE_M];
  __shared__ float s_align[TILE_M];

  int tid = threadIdx.x;
  int b  = blockIdx.x >> 6;              // 64 chunks of 32 rows per batch
  int t0 = (blockIdx.x & 63) << 5;

  int w = tid >> 6, l = tid & 63;
  int quad = l >> 4, lrow = l & 15;
  int acol0 = w*32 + lrow;               // nt=0 column of this wave
  int acol1 = acol0 + 16;                // nt=1 column
  const bf16x8* wv = (const bf16x8*)Wext;   // index = kg*Asz + acol

  // prefetch kc=0 B-fragments (independent of LDS; in flight during staging)
  bf16x8 bnext0 = wv[quad*Asz + acol0];
  bf16x8 bnext1 = wv[quad*Asz + acol1];

  // stage memory tile fp32 -> bf16 LDS (nt float4 loads, 16 per thread)
  const f32x4* memv = (const f32x4*)(memory + (size_t)(b*Tsz + t0)*Esz);
  #pragma unroll
  for (int p = 0; p < 16; ++p) {
    int i = tid + p*256;
    int r = i >> 7, c4 = i & 127;
    f32x4 v = __builtin_nontemporal_load(memv + r*128 + c4);
    int k = c4 * 4;
    int sw = (k >> 3) ^ (r & 7);
    int base = r*KP + sw*8 + (k & 7);
    bf16x4 pk; pk[0]=(bf16)v[0]; pk[1]=(bf16)v[1]; pk[2]=(bf16)v[2]; pk[3]=(bf16)v[3];
    *(bf16x4*)&Afull[base] = pk;
  }
  // stage im2col'd aw window into K columns 512..575 (32x64 = 8 per thread)
  const float* aw = awcat + (size_t)b*2*Tsz;
  #pragma unroll
  for (int p = 0; p < 8; ++p) {
    int i = tid + p*256;
    int r = i >> 6, j = i & 63;
    float val = 0.f;
    if (j < 62) {
      int c  = (j < 31) ? 0 : 1;
      int kk = (j < 31) ? j : j - 31;
      int t  = t0 + r + kk - 15;
      if (t >= 0 && t < Tsz) val = aw[c*Tsz + t];
    }
    int k = Esz + j;
    int sw = (k >> 3) ^ (r & 7);
    Afull[r*KP + sw*8 + (k & 7)] = (bf16)val;
  }
  if (tid < Asz) { s_pq[tid] = pq[b*Asz + tid]; s_vw[tid] = vw[tid]; }
  if (tid < TILE_M) s_ebuf[tid] = 0.f;
  __syncthreads();

  f32x4 acc[2][2];                        // [mt][nt]
  #pragma unroll
  for (int mt = 0; mt < 2; ++mt)
    #pragma unroll
    for (int nt = 0; nt < 2; ++nt)
      acc[mt][nt] = (f32x4){0.f, 0.f, 0.f, 0.f};

  // K loop: 18 chunks of 32 (512 memory + 64 location), B pipelined 1 ahead
  for (int kc = 0; kc < KP/32; ++kc) {
    bf16x8 bfrag0 = bnext0, bfrag1 = bnext1;
    if (kc < KP/32 - 1) {
      int kg2 = (kc+1)*4 + quad;
      bnext0 = wv[kg2*Asz + acol0];
      bnext1 = wv[kg2*Asz + acol1];
    }
    int kg = kc*4 + quad;
    bf16x8 afrag[2];
    #pragma unroll
    for (int mt = 0; mt < 2; ++mt) {
      int row = mt*16 + lrow;
      afrag[mt] = *(const bf16x8*)&Afull[row*KP + ((kg ^ (row & 7)) << 3)];
    }
    #pragma unroll
    for (int mt = 0; mt < 2; ++mt) {
      acc[mt][0] = __builtin_amdgcn_mfma_f32_16x16x32_bf16(afrag[mt], bfrag0, acc[mt][0], 0, 0, 0);
      acc[mt][1] = __builtin_amdgcn_mfma_f32_16x16x32_bf16(afrag[mt], bfrag1, acc[mt][1], 0, 0, 0);
    }
  }

  // energies: e_r = sum_a tanh(pm+pl+pq)*v_w   (C layout: col=lane&15, row=quad*4+reg)
  float partial[2][4];
  #pragma unroll
  for (int mt = 0; mt < 2; ++mt)
    #pragma unroll
    for (int rg = 0; rg < 4; ++rg) partial[mt][rg] = 0.f;
  #pragma unroll
  for (int nt = 0; nt < 2; ++nt) {
    int col = w*32 + nt*16 + lrow;
    float vwc = s_vw[col], pqc = s_pq[col];
    #pragma unroll
    for (int mt = 0; mt < 2; ++mt)
      #pragma unroll
      for (int rg = 0; rg < 4; ++rg)
        partial[mt][rg] += tanh_fast(acc[mt][nt][rg] + pqc) * vwc;
  }
  #pragma unroll
  for (int off = 1; off < 16; off <<= 1)
    #pragma unroll
    for (int mt = 0; mt < 2; ++mt)
      #pragma unroll
      for (int rg = 0; rg < 4; ++rg)
        partial[mt][rg] += __shfl_xor(partial[mt][rg], off, 64);
  if (lrow == 0) {
    #pragma unroll
    for (int mt = 0; mt < 2; ++mt)
      #pragma unroll
      for (int rg = 0; rg < 4; ++rg)
        atomicAdd(&s_ebuf[mt*16 + quad*4 + rg], partial[mt][rg]);
  }
  __syncthreads();

  if (tid < TILE_M) {
    int t = t0 + tid;
    float al = s_ebuf[tid] + vb[0] + (float)mask[b*Tsz + t] * -1e25f;
    s_align[tid] = al;
    ws_align[b*Tsz + t] = al;
  }
  __syncthreads();

  // attention_output partial: sum_r align[r] * mem[r,e] over this 32-row chunk
  int k0 = tid * 2;           // paired adjacent columns -> 4B LDS reads
  float a0 = 0.f, a1 = 0.f;
  #pragma unroll
  for (int r = 0; r < TILE_M; ++r) {
    float al = s_align[r];
    int sw = ((k0 >> 3) ^ (r & 7));
    bf16x2 m = *(const bf16x2*)&Afull[r*KP + sw*8 + (k0 & 7)];
    a0 += al * (float)m[0];
    a1 += al * (float)m[1];
  }
  if constexpr (USE_POUT) {
    float2 o; o.x = a0; o.y = a1;
    *(float2*)&pout[(size_t)blockIdx.x * Esz + k0] = o;   // plain coalesced store
  } else {
    atomicAdd(&outg[b*Esz + k0],     a0);
    atomicAdd(&outg[b*Esz + k0 + 1], a1);
  }
}

// ---------------- softmax over T per batch row (+ optional out reduction) ----
template<bool REDUCE>
__global__ __launch_bounds__(256) void softmax_kernel(
    const float* __restrict__ ws_align, const float* __restrict__ pout,
    float* __restrict__ out_be, float* __restrict__ out_w)
{
  int b = blockIdx.x, tid = threadIdx.x;
  const float* row = ws_align + (size_t)b*Tsz;
  float vals[8];
  float lmax = -3.4e38f;
  #pragma unroll
  for (int i = 0; i < 8; ++i) { vals[i] = row[tid + i*256]; lmax = fmaxf(lmax, vals[i]); }
  #pragma unroll
  for (int off = 1; off < 64; off <<= 1) lmax = fmaxf(lmax, __shfl_xor(lmax, off, 64));
  __shared__ float smax[4], ssum[4];
  if ((tid & 63) == 0) smax[tid >> 6] = lmax;
  __syncthreads();
  float bmax = fmaxf(fmaxf(smax[0], smax[1]), fmaxf(smax[2], smax[3]));
  float lsum = 0.f;
  #pragma unroll
  for (int i = 0; i < 8; ++i) { vals[i] = __expf(vals[i] - bmax); lsum += vals[i]; }
  #pragma unroll
  for (int off = 1; off < 64; off <<= 1) lsum += __shfl_xor(lsum, off, 64);
  if ((tid & 63) == 0) ssum[tid >> 6] = lsum;
  __syncthreads();
  float inv = 1.f / (ssum[0] + ssum[1] + ssum[2] + ssum[3]);
  #pragma unroll
  for (int i = 0; i < 8; ++i) out_w[(size_t)b*Tsz + tid + i*256] = vals[i] * inv;

  if constexpr (REDUCE) {
    // out[b,e] = sum_{c<CHUNKS} pout[(b*CHUNKS+c)*E + e]   (8 MB L2-warm read)
    float2 s; s.x = 0.f; s.y = 0.f;
    const float2* pv = (const float2*)(pout + (size_t)b*CHUNKS*Esz) + tid;
    #pragma unroll
    for (int c = 0; c < CHUNKS; ++c) {
      float2 v = pv[(size_t)c * (Esz/2)];
      s.x += v.x; s.y += v.y;
    }
    *(float2*)&out_be[(size_t)b*Esz + tid*2] = s;
  }
}

extern "C" void kernel_launch(void* const* d_in, const int* in_sizes, int n_in,
                              void* d_out, int out_size, void* d_ws, size_t ws_size,
                              hipStream_t stream) {
  const float* ah   = (const float*)d_in[0];
  const float* mem  = (const float*)d_in[1];
  const float* awc  = (const float*)d_in[2];
  const int*   mask = (const int*)d_in[3];
  const float* Wq   = (const float*)d_in[4];
  const float* Wm   = (const float*)d_in[5];
  const float* cw   = (const float*)d_in[6];
  const float* Wl   = (const float*)d_in[7];
  const float* vw   = (const float*)d_in[8];
  const float* vb   = (const float*)d_in[9];
  float* out = (float*)d_out;

  // ws layout: Wext bf16 [72][128][8] (147456 B) | pq f32 (32768 B)
  //            | align f32 [64][2048] (524288 B) | pout f32 [4096][512] (8 MB)
  bf16*  Wext = (bf16*)d_ws;
  float* pq   = (float*)((char*)d_ws + 147456);
  float* wsa  = (float*)((char*)d_ws + 180224);
  float* pout = (float*)((char*)d_ws + 180224 + (size_t)Bsz*Tsz*4);

  size_t need = 180224 + (size_t)Bsz*Tsz*4 + (size_t)Bsz*CHUNKS*Esz*4;

  prep_kernel<<<dim3(224), 256, 0, stream>>>(Wm, cw, Wl, ah, Wq, Wext, pq);
  if (ws_size >= need) {
    attn_main<true><<<dim3(Bsz*CHUNKS), 256, 0, stream>>>(
        mem, awc, mask, Wext, pq, vw, vb, pout, out, wsa);
    softmax_kernel<true><<<dim3(Bsz), 256, 0, stream>>>(wsa, pout, out, out + Bsz*Esz);
  } else {
    // fallback: round-0-verified atomic epilogue (no pout buffer needed)
    hipMemsetAsync(out, 0, Bsz*Esz*sizeof(float), stream);
    attn_main<false><<<dim3(Bsz*CHUNKS), 256, 0, stream>>>(
        mem, awc, mask, Wext, pq, vw, vb, wsa /*unused*/, out, wsa);
    softmax_kernel<false><<<dim3(Bsz), 256, 0, stream>>>(wsa, wsa, out, out + Bsz*Esz);
  }
}